// Round 1
// baseline (163.540 us; speedup 1.0000x reference)
//
#include <hip/hip_runtime.h>

// NonImagingRod: per-ray damped-Newton (LM) root find on f(t) = A t^2 + B t + C,
// where A,B,C are per-ray coefficients of the implicit paraboloid evaluated
// along the ray in the rod's local frame. 31 iterations (30 warmup + 1 final),
// then loss = loss_in + mean(f(t_final)^2)  (scale term == 1.0).

#define LM_ITERS 31
constexpr float DAMPING   = 0.5f;
constexpr float MAX_DELTA = 1000.0f;

__global__ __launch_bounds__(256) void rod_kernel(
    const float* __restrict__ P, const float* __restrict__ V,
    const float* __restrict__ Rm, const float* __restrict__ Tv,
    const float* __restrict__ c_ptr, double* __restrict__ ws, int n)
{
    const float c  = c_ptr[0];
    const float r00 = Rm[0], r01 = Rm[1], r02 = Rm[2];
    const float r10 = Rm[3], r11 = Rm[4], r12 = Rm[5];
    const float r20 = Rm[6], r21 = Rm[7], r22 = Rm[8];
    const float t0 = Tv[0], t1 = Tv[1], t2 = Tv[2];

    const int tid  = blockIdx.x * blockDim.x + threadIdx.x;
    const int base = tid * 4;

    double acc = 0.0;
    if (base < n) {
        // 4 rays per thread: 3 float4 loads from each of P and V (n % 4 == 0).
        const float4* P4 = (const float4*)P;
        const float4* V4 = (const float4*)V;
        float4 pa = P4[tid * 3 + 0], pb = P4[tid * 3 + 1], pcv = P4[tid * 3 + 2];
        float4 va = V4[tid * 3 + 0], vb = V4[tid * 3 + 1], vcv = V4[tid * 3 + 2];

        const float px[4] = {pa.x, pa.w, pb.z, pcv.y};
        const float py[4] = {pa.y, pb.x, pb.w, pcv.z};
        const float pz[4] = {pa.z, pb.y, pcv.x, pcv.w};
        const float vx[4] = {va.x, va.w, vb.z, vcv.y};
        const float vy[4] = {va.y, vb.x, vb.w, vcv.z};
        const float vz[4] = {va.z, vb.y, vcv.x, vcv.w};

        float A[4], A2[4], B[4], C[4], tt[4];
        #pragma unroll
        for (int r = 0; r < 4; ++r) {
            // local frame: Pl = (P - T) @ R, Vl = V @ R  (row-vector times R)
            const float qx = px[r] - t0, qy = py[r] - t1, qz = pz[r] - t2;
            const float plx = qx * r00 + qy * r10 + qz * r20;
            const float ply = qx * r01 + qy * r11 + qz * r21;
            const float plz = qx * r02 + qy * r12 + qz * r22;
            const float vlx = vx[r] * r00 + vy[r] * r10 + vz[r] * r20;
            const float vly = vx[r] * r01 + vy[r] * r11 + vz[r] * r21;
            const float vlz = vx[r] * r02 + vy[r] * r12 + vz[r] * r22;
            A[r]  = -c * (vly * vly + vlz * vlz);
            B[r]  = vlx - 2.0f * c * (ply * vly + plz * vlz);
            C[r]  = plx - c * (ply * ply + plz * plz);
            A2[r] = A[r] + A[r];
            tt[r] = 0.0f;
        }

        #pragma unroll 1
        for (int it = 0; it < LM_ITERS; ++it) {
            #pragma unroll
            for (int r = 0; r < 4; ++r) {
                const float fp  = fmaf(A2[r], tt[r], B[r]);
                const float f   = fmaf(fmaf(A[r], tt[r], B[r]), tt[r], C[r]);
                const float den = fmaf(fp, fp, DAMPING);
                const float num = f * fp;
                // v_rcp_f32 is ~1 ulp on CDNA; LM iteration is self-correcting.
                float delta = num * __builtin_amdgcn_rcpf(den);
                delta = fminf(fmaxf(delta, -MAX_DELTA), MAX_DELTA);
                tt[r] -= delta;
            }
        }

        #pragma unroll
        for (int r = 0; r < 4; ++r) {
            if (base + r < n) {
                const float f = fmaf(fmaf(A[r], tt[r], B[r]), tt[r], C[r]);
                acc += (double)(f * f);
            }
        }
    }

    // wave(64) shuffle reduce -> LDS across 4 waves -> one f64 atomic per block
    for (int off = 32; off > 0; off >>= 1)
        acc += __shfl_down(acc, off, 64);
    __shared__ double sacc[4];
    const int lane = threadIdx.x & 63, wave = threadIdx.x >> 6;
    if (lane == 0) sacc[wave] = acc;
    __syncthreads();
    if (threadIdx.x == 0) {
        atomicAdd(ws, sacc[0] + sacc[1] + sacc[2] + sacc[3]);
    }
}

__global__ void rod_finalize(const double* __restrict__ ws,
                             const float* __restrict__ loss_in,
                             float* __restrict__ out, double inv_n)
{
    out[0] = (float)(ws[0] * inv_n + (double)loss_in[0]);
}

extern "C" void kernel_launch(void* const* d_in, const int* in_sizes, int n_in,
                              void* d_out, int out_size, void* d_ws, size_t ws_size,
                              hipStream_t stream) {
    const float* P       = (const float*)d_in[0];
    const float* V       = (const float*)d_in[1];
    const float* R       = (const float*)d_in[2];
    const float* T       = (const float*)d_in[3];
    const float* c       = (const float*)d_in[4];
    const float* loss_in = (const float*)d_in[5];

    const int n = in_sizes[0] / 3;           // number of rays

    // d_ws is poisoned to 0xAA before every launch — zero the accumulator.
    hipMemsetAsync(d_ws, 0, sizeof(double), stream);

    const int threads = (n + 3) / 4;         // 4 rays per thread
    const int block   = 256;
    const int grid    = (threads + block - 1) / block;
    rod_kernel<<<grid, block, 0, stream>>>(P, V, R, T, c, (double*)d_ws, n);
    rod_finalize<<<1, 1, 0, stream>>>((const double*)d_ws, loss_in,
                                      (float*)d_out, 1.0 / (double)n);
}